// Round 11
// baseline (71.860 us; speedup 1.0000x reference)
//
#include <hip/hip_runtime.h>

#define NEG_BIG (-3.0e38f)

// R9 kernel (72.0us, passing) with ONE change: __launch_bounds__(512, 6).
// Evidence: occupancy stuck at ~57% == 5 waves/SIMD == VGPR in (85..102];
// LDS allows 32 waves/CU, so VGPR is the cap. The (512,6) bound caps VGPR
// at 85; the R9 ring structure's live set (~60 floats) fits -> 6 waves/SIMD.
// (R3's spill was the dual-window structure at a forced 64-VGPR cap; this
// is the single-window 5+3-ring structure at 85.)
//
// One block = 8 waves (512 thr); each wave handles 2 samples (one per 32-lane
// half). Lane m owns 8 lags sh = (248-8m)+q, q=0..7 (sh=255 dummy).
// Window W[t] = apad[8m+4c+t], t=0..11 (slots 2m+c .. 2m+c+2).
// Per-half region = 528 floats (2112 B == 64 mod 128 -> halves land on
// complementary bank-groups; structural 8-phase minimum per wave b128).
//   apad slots 0..95: zeros[0,128) | raw audio [128,256) | zeros [256,384)
//   video floats [384,512) (slots 96..127), pad [512,528).
// corr_raw[sh] = sum_j v[j]*apad[j-sh+255]; acc[q] += v[4c+e]*W[7+e-q].
__global__ __launch_bounds__(512, 6) void avsync_kernel(
    const float* __restrict__ video, const float* __restrict__ audio,
    const float* __restrict__ W1, const float* __restrict__ b1,
    const float* __restrict__ W2, const float* __restrict__ b2,
    float* __restrict__ out) {
  __shared__ float lds[8448];   // 8 waves * 2 halves * 528 floats

  const int tid  = threadIdx.x;
  const int wid  = tid >> 6;
  const int lane = tid & 63;
  const int half = lane >> 5;
  const int m    = lane & 31;
  const int b    = (int)blockIdx.x * 16 + wid * 2 + half;

  float* hbase = &lds[(wid * 2 + half) * 528];

  const float4 v4 = *reinterpret_cast<const float4*>(video + (size_t)b * 128 + 4 * m);
  const float4 a4 = *reinterpret_cast<const float4*>(audio + (size_t)b * 128 + 4 * m);

  // ---- stage raw data (wave-private region, no barrier needed) ----
  float4 z4; z4.x = z4.y = z4.z = z4.w = 0.0f;
  float4* sl = reinterpret_cast<float4*>(hbase);
  sl[m]      = z4;        // apad slots [0,32)   = zeros
  sl[64 + m] = z4;        // apad slots [64,96)  = zeros
  sl[32 + m] = a4;        // apad slots [32,64)  = raw audio
  sl[96 + m] = v4;        // video
  // ---- norms (per half) ----
  float pv = v4.x * v4.x + v4.y * v4.y + v4.z * v4.z + v4.w * v4.w;
  float pa = a4.x * a4.x + a4.y * a4.y + a4.z * a4.z + a4.w * a4.w;
#pragma unroll
  for (int off = 1; off < 32; off <<= 1) {
    pv += __shfl_xor(pv, off, 32);
    pa += __shfl_xor(pa, off, 32);
  }
  const float nv = sqrtf(pv);
  const float na = sqrtf(pa);
  const float iv = 1.0f / fmaxf(nv, 1e-12f);
  const float ia = 1.0f / fmaxf(na, 1e-12f);

  // ---- phase statistic on normalized difference ----
  const float d0 = v4.x * iv - a4.x * ia;
  const float d1 = v4.y * iv - a4.y * ia;
  const float d2 = v4.z * iv - a4.z * ia;
  const float d3 = v4.w * iv - a4.w * ia;
  float sc = __cosf(d0) + __cosf(d1) + __cosf(d2) + __cosf(d3);
  float ss = __sinf(d0) + __sinf(d1) + __sinf(d2) + __sinf(d3);
#pragma unroll
  for (int off = 1; off < 32; off <<= 1) {
    sc += __shfl_xor(sc, off, 32);
    ss += __shfl_xor(ss, off, 32);
  }

  // ---- corr-independent stats precompute (small loop-carried set) ----
  const float s_norm = iv * ia;
  const float rv = nv / fmaxf(nv, 1e-12f);
  const float ra = na / fmaxf(na, 1e-12f);
  const float rvra = rv * ra;
  const float er = (rv * rv) / (ra * ra + 1e-6f);
  const float mc = sc * (1.0f / 128.0f), ms = ss * (1.0f / 128.0f);
  const float pc = sqrtf(mc * mc + ms * ms);

  // ---- main correlation: single stride-2 window, immediate offsets ----
  const float4* wbase = reinterpret_cast<const float4*>(hbase) + 2 * m;
  const float4* vbase = reinterpret_cast<const float4*>(hbase) + 96;

  float acc0 = 0.f, acc1 = 0.f, acc2 = 0.f, acc3 = 0.f;
  float acc4 = 0.f, acc5 = 0.f, acc6 = 0.f, acc7 = 0.f;

  float4 P0 = wbase[0], P1 = wbase[1], P2 = wbase[2], P3 = wbase[3], P4;
  float4 Q0 = vbase[0], Q1 = vbase[1], Q2;

  // chunk c: A=P[c%5], B=P[(c+1)%5], C=P[(c+2)%5], read wbase[c+4] -> P[(c+4)%5];
  //          VA=Q[c%3], read vbase[c+2] -> Q[(c+2)%3].  Reads only for c<30.
#define CHUNK(c, A, B, C, D, VA, VQ)                                           \
  do {                                                                         \
    if ((c) < 30) {                                                            \
      (D)  = wbase[(c) + 4];                                                   \
      (VQ) = vbase[(c) + 2];                                                   \
    }                                                                          \
    acc0 = fmaf((VA).x, (B).w, acc0); acc0 = fmaf((VA).y, (C).x, acc0);        \
    acc0 = fmaf((VA).z, (C).y, acc0); acc0 = fmaf((VA).w, (C).z, acc0);        \
    acc1 = fmaf((VA).x, (B).z, acc1); acc1 = fmaf((VA).y, (B).w, acc1);        \
    acc1 = fmaf((VA).z, (C).x, acc1); acc1 = fmaf((VA).w, (C).y, acc1);        \
    acc2 = fmaf((VA).x, (B).y, acc2); acc2 = fmaf((VA).y, (B).z, acc2);        \
    acc2 = fmaf((VA).z, (B).w, acc2); acc2 = fmaf((VA).w, (C).x, acc2);        \
    acc3 = fmaf((VA).x, (B).x, acc3); acc3 = fmaf((VA).y, (B).y, acc3);        \
    acc3 = fmaf((VA).z, (B).z, acc3); acc3 = fmaf((VA).w, (B).w, acc3);        \
    acc4 = fmaf((VA).x, (A).w, acc4); acc4 = fmaf((VA).y, (B).x, acc4);        \
    acc4 = fmaf((VA).z, (B).y, acc4); acc4 = fmaf((VA).w, (B).z, acc4);        \
    acc5 = fmaf((VA).x, (A).z, acc5); acc5 = fmaf((VA).y, (A).w, acc5);        \
    acc5 = fmaf((VA).z, (B).x, acc5); acc5 = fmaf((VA).w, (B).y, acc5);        \
    acc6 = fmaf((VA).x, (A).y, acc6); acc6 = fmaf((VA).y, (A).z, acc6);        \
    acc6 = fmaf((VA).z, (A).w, acc6); acc6 = fmaf((VA).w, (B).x, acc6);        \
    acc7 = fmaf((VA).x, (A).x, acc7); acc7 = fmaf((VA).y, (A).y, acc7);        \
    acc7 = fmaf((VA).z, (A).z, acc7); acc7 = fmaf((VA).w, (A).w, acc7);        \
  } while (0)

  CHUNK( 0, P0, P1, P2, P4, Q0, Q2);
  CHUNK( 1, P1, P2, P3, P0, Q1, Q0);
  CHUNK( 2, P2, P3, P4, P1, Q2, Q1);
  CHUNK( 3, P3, P4, P0, P2, Q0, Q2);
  CHUNK( 4, P4, P0, P1, P3, Q1, Q0);
  CHUNK( 5, P0, P1, P2, P4, Q2, Q1);
  CHUNK( 6, P1, P2, P3, P0, Q0, Q2);
  CHUNK( 7, P2, P3, P4, P1, Q1, Q0);
  CHUNK( 8, P3, P4, P0, P2, Q2, Q1);
  CHUNK( 9, P4, P0, P1, P3, Q0, Q2);
  CHUNK(10, P0, P1, P2, P4, Q1, Q0);
  CHUNK(11, P1, P2, P3, P0, Q2, Q1);
  CHUNK(12, P2, P3, P4, P1, Q0, Q2);
  CHUNK(13, P3, P4, P0, P2, Q1, Q0);
  CHUNK(14, P4, P0, P1, P3, Q2, Q1);
  CHUNK(15, P0, P1, P2, P4, Q0, Q2);
  CHUNK(16, P1, P2, P3, P0, Q1, Q0);
  CHUNK(17, P2, P3, P4, P1, Q2, Q1);
  CHUNK(18, P3, P4, P0, P2, Q0, Q2);
  CHUNK(19, P4, P0, P1, P3, Q1, Q0);
  CHUNK(20, P0, P1, P2, P4, Q2, Q1);
  CHUNK(21, P1, P2, P3, P0, Q0, Q2);
  CHUNK(22, P2, P3, P4, P1, Q1, Q0);
  CHUNK(23, P3, P4, P0, P2, Q2, Q1);
  CHUNK(24, P4, P0, P1, P3, Q0, Q2);
  CHUNK(25, P0, P1, P2, P4, Q1, Q0);
  CHUNK(26, P1, P2, P3, P0, Q2, Q1);
  CHUNK(27, P2, P3, P4, P1, Q0, Q2);
  CHUNK(28, P3, P4, P0, P2, Q1, Q0);
  CHUNK(29, P4, P0, P1, P3, Q2, Q1);
  CHUNK(30, P0, P1, P2, P4, Q0, Q2);
  CHUNK(31, P1, P2, P3, P0, Q1, Q0);
#undef CHUNK

  // ---- per-lane stats: 8 lags, sh = (248-8m)+q ascending in q ----
  const float accv[8] = {acc0, acc1, acc2, acc3, acc4, acc5, acc6, acc7};
  const int sh0 = 248 - 8 * m;
  float sum = 0.f, ssq = 0.f, mx = NEG_BIG;
  int mi = 0;
#pragma unroll
  for (int q = 0; q < 8; ++q) {
    const int sh = sh0 + q;
    const bool realLag = (sh < 255);
    const float cv = accv[q];
    const float cs = realLag ? cv : 0.f;
    sum += cs;
    ssq = fmaf(cs, cs, ssq);
    const float cm = realLag ? cv : NEG_BIG;
    if (cm > mx) { mx = cm; mi = sh; }
  }
  // cross-lane reduce over the 32-lane half (max with min-index tie-break)
#pragma unroll
  for (int off = 1; off < 32; off <<= 1) {
    const float ov = __shfl_xor(mx, off, 32);
    const int   oi = __shfl_xor(mi, off, 32);
    if (ov > mx || (ov == mx && oi < mi)) { mx = ov; mi = oi; }
    sum += __shfl_xor(sum, off, 32);
    ssq += __shfl_xor(ssq, off, 32);
  }

  // ---- finalize stats (corr_normalized = s_norm * corr_raw) ----
  const float delay = (float)mi - 127.0f;
  const float cstr = (mx * s_norm) / (rvra + 1e-6f);
  const float mean_r = sum * (1.0f / 255.0f);
  const float var_r  = fmaxf(ssq * (1.0f / 255.0f) - mean_r * mean_r, 0.0f);
  const float cstd = s_norm * sqrtf(var_r);
  const float cons = 1.0f / (1.0f + fabsf(delay));

  const float s0 = delay * 0.1f;
  const float s1 = cstr;
  const float s2 = cstd;
  const float s3 = er;
  const float s4 = pc;
  const float s5 = cons;

  // ---- MLP: lane m of each half computes output feature m ----
  float h[16];
#pragma unroll
  for (int k = 0; k < 16; ++k) {
    float acch = b1[k];
    acch = fmaf(s0, W1[0 * 16 + k], acch);
    acch = fmaf(s1, W1[1 * 16 + k], acch);
    acch = fmaf(s2, W1[2 * 16 + k], acch);
    acch = fmaf(s3, W1[3 * 16 + k], acch);
    acch = fmaf(s4, W1[4 * 16 + k], acch);
    acch = fmaf(s5, W1[5 * 16 + k], acch);
    h[k] = fmaxf(acch, 0.0f);
  }
  float o = b2[m];
#pragma unroll
  for (int k = 0; k < 16; ++k) o = fmaf(h[k], W2[k * 32 + m], o);
  out[(size_t)b * 32 + m] = o;
}

extern "C" void kernel_launch(void* const* d_in, const int* in_sizes, int n_in,
                              void* d_out, int out_size, void* d_ws, size_t ws_size,
                              hipStream_t stream) {
  const float* video = (const float*)d_in[0];
  const float* audio = (const float*)d_in[1];
  const float* W1 = (const float*)d_in[2];
  const float* b1 = (const float*)d_in[3];
  const float* W2 = (const float*)d_in[4];
  const float* b2 = (const float*)d_in[5];
  float* out = (float*)d_out;

  const int B = in_sizes[0] / 128;        // 65536 samples
  const int blocks = B / 16;              // 2 samples/wave * 8 waves/block
  avsync_kernel<<<blocks, 512, 0, stream>>>(video, audio, W1, b1, W2, b2, out);
}